// Round 10
// baseline (5264.591 us; speedup 1.0000x reference)
//
#include <hip/hip_runtime.h>
#include <hip/hip_fp16.h>

typedef _Float16 f16;
typedef _Float16 f16x2 __attribute__((ext_vector_type(2)));
typedef _Float16 f16x8 __attribute__((ext_vector_type(8)));
typedef float f32x4 __attribute__((ext_vector_type(4)));

#define B_    32
#define T_    2048
#define E_    512
#define H_    256
#define G4_   1024
#define VOCAB_ 50257

// ---------------- workspace layout (bytes) ----------------
static const size_t WS_XG   = 0;            // f16 [65536][1024] = 134217728
static const size_t WS_WIH  = 134217728ull; // f16 [1024][512]   = 1048576
static const size_t WS_WREG = 135266304ull; // uint4 [45][512]   = 368640
static const size_t WS_WLDS = 135634944ull; // uint4 [8][19][64] = 155648
static const size_t WS_MB   = 135790592ull; // u32 [32][64]      = 8192
static const size_t WS_BSUM = 135798784ull; // f32 [1024]        = 4096
static const size_t WS_POOL = 135802880ull; // f32 [32][256]     = 32768

// recur dynamic LDS: [0,155648) B-frags [wv][s19][lane]x16B; [155648,+1024) h dbuf
#define HB_OFF   155648
#define LDS_BYTES 156672

__device__ __forceinline__ unsigned pack2f(float a, float b) {
    f16x2 h; h.x = (f16)a; h.y = (f16)b;
    return __builtin_bit_cast(unsigned, h);
}

__device__ __forceinline__ float sigm(float v) {
    return 1.f / (1.f + exp2f(-1.44269504f * v));
}
__device__ __forceinline__ float tanhr(float v) {
    float t = exp2f(-2.88539008f * fabsf(v));   // e^(-2|v|)
    float r = (1.f - t) / (1.f + t);
    return v < 0.f ? -r : r;
}

__device__ __forceinline__ int detect64(const int* x) {
    return (x[1] == 0 && x[3] == 0 && x[5] == 0) ? 1 : 0;
}

// ---------------- prep (identical to the passing round-8 version) ----------------
// recur MFMA geometry: wave wv owns n-tiles nt = q*16 + wv*2 + c (q=0..3,c=0..1),
// i.e. gates G = q*256 + wv*32 + c*16 + (lane&15); k-tiles kt=0..7 (32 k each).
// B-frag(nt,kt): lane holds W[G][k = kt*32 + (lane>>4)*8 .. +8] (f16x8 = uint4).
// Register frags f<45: f = kt*8+qc (kt<5), f = 40+qc (kt=5, qc<5).
// LDS frags s<19: s<3 -> kt=5,qc=5+s; s<11 -> kt=6,qc=s-3; else kt=7,qc=s-11.
__global__ void prep_k(const int* __restrict__ x,
                       const float* __restrict__ w_ih, const float* __restrict__ w_hh,
                       const float* __restrict__ b_ih, const float* __restrict__ b_hh,
                       f16* __restrict__ wih16, uint4* __restrict__ wreg,
                       uint4* __restrict__ wlds, unsigned* __restrict__ mb,
                       float* __restrict__ bsum)
{
    const int gid = blockIdx.x * blockDim.x + threadIdx.x;
    const int stride = gridDim.x * blockDim.x;
    const int is64 = detect64(x);
    for (int i = gid; i < G4_*E_; i += stride) wih16[i] = (f16)w_ih[i];
    for (int i = gid; i < G4_; i += stride) bsum[i] = b_ih[i] + b_hh[i];
    for (int n = gid; n < 45*512; n += stride) {
        const int f = n >> 9, tid = n & 511;
        const int wv = tid >> 6, lane = tid & 63, li = lane & 15, lq = lane >> 4;
        int kt, qc;
        if (f < 40) { kt = f >> 3; qc = f & 7; } else { kt = 5; qc = f - 40; }
        const int q = qc >> 1, c = qc & 1;
        const int G = q*256 + wv*32 + c*16 + li;
        const int k0 = kt*32 + lq*8;
        const float* src = w_hh + (size_t)G*H_ + k0;
        uint4 v;
        v.x = pack2f(src[0], src[1]); v.y = pack2f(src[2], src[3]);
        v.z = pack2f(src[4], src[5]); v.w = pack2f(src[6], src[7]);
        wreg[n] = v;
    }
    for (int n = gid; n < 8*19*64; n += stride) {
        const int lane = n & 63, sw = n >> 6;
        const int s = sw % 19, wv = sw / 19;
        int kt, qc;
        if (s < 3)       { kt = 5; qc = 5 + s; }
        else if (s < 11) { kt = 6; qc = s - 3; }
        else             { kt = 7; qc = s - 11; }
        const int q = qc >> 1, c = qc & 1;
        const int G = q*256 + wv*32 + c*16 + (lane & 15);
        const int k0 = kt*32 + (lane >> 4)*8;
        const float* src = w_hh + (size_t)G*H_ + k0;
        uint4 v;
        v.x = pack2f(src[0], src[1]); v.y = pack2f(src[2], src[3]);
        v.z = pack2f(src[4], src[5]); v.w = pack2f(src[6], src[7]);
        wlds[n] = v;
    }
    for (int i = gid; i < 32*64; i += stride) {
        const int b = i >> 6, wd = i & 63;
        unsigned word = 0;
        for (int tt = 0; tt < 32; ++tt) {
            const size_t ti = ((size_t)b*T_ + wd*32 + tt) << is64;
            word |= (x[ti] != 0 ? 1u : 0u) << tt;
        }
        mb[i] = word;
    }
}

// ---------------- GEMM: xg[t][j*4+gt] = (f16(emb[x]) @ f16(w_ih)^T + bsum) permuted ----------------
__global__ __launch_bounds__(256) void gemm_xg_k(
    const int* __restrict__ x, const float* __restrict__ emb,
    const f16* __restrict__ wih, const float* __restrict__ bsum,
    f16* __restrict__ xg)
{
    __shared__ f16 As[128*32];
    __shared__ f16 Bs[128*32];
    const int tid = threadIdx.x;
    const int bid = blockIdx.x;
    const int mt = bid >> 3, nt = bid & 7;
    const int wv = tid >> 6, lane = tid & 63;
    const int wm = wv & 1, wn = wv >> 1;
    const int ml = lane & 15, kg = lane >> 4;
    const int is64 = detect64(x);
    const int r = tid >> 1, kh = tid & 1;
    int tok = x[(size_t)(mt*128 + r) << is64];
    tok = tok < 0 ? 0 : (tok >= VOCAB_ ? VOCAB_ - 1 : tok);
    const float* arow = emb + (size_t)tok * E_ + kh*16;
    const f16*   brow = wih + (size_t)(nt*128 + r) * E_ + kh*16;

    f32x4 acc[4][4] = {};
    for (int kk = 0; kk < 16; ++kk) {
        const int k0 = kk * 32;
        float4 a0 = *(const float4*)(arow + k0 + 0);
        float4 a1 = *(const float4*)(arow + k0 + 4);
        float4 a2 = *(const float4*)(arow + k0 + 8);
        float4 a3 = *(const float4*)(arow + k0 + 12);
        uint4 bu0 = *(const uint4*)(brow + k0);
        uint4 bu1 = *(const uint4*)(brow + k0 + 8);
        uint4 au0, au1;
        au0.x = pack2f(a0.x, a0.y); au0.y = pack2f(a0.z, a0.w);
        au0.z = pack2f(a1.x, a1.y); au0.w = pack2f(a1.z, a1.w);
        au1.x = pack2f(a2.x, a2.y); au1.y = pack2f(a2.z, a2.w);
        au1.z = pack2f(a3.x, a3.y); au1.w = pack2f(a3.z, a3.w);
        __syncthreads();
        *(uint4*)(&As[r*32 + kh*16 + 0]) = au0;
        *(uint4*)(&As[r*32 + kh*16 + 8]) = au1;
        *(uint4*)(&Bs[r*32 + kh*16 + 0]) = bu0;
        *(uint4*)(&Bs[r*32 + kh*16 + 8]) = bu1;
        __syncthreads();
        f16x8 af[4], bf[4];
        #pragma unroll
        for (int i = 0; i < 4; ++i) {
            af[i] = *(const f16x8*)(&As[(wm*64 + i*16 + ml)*32 + kg*8]);
            bf[i] = *(const f16x8*)(&Bs[(wn*64 + i*16 + ml)*32 + kg*8]);
        }
        #pragma unroll
        for (int i = 0; i < 4; ++i)
            #pragma unroll
            for (int j = 0; j < 4; ++j)
                acc[i][j] = __builtin_amdgcn_mfma_f32_16x16x32_f16(af[i], bf[j], acc[i][j], 0, 0, 0);
    }
    #pragma unroll
    for (int j = 0; j < 4; ++j) {
        const int gc = nt*128 + wn*64 + j*16 + ml;
        const float bs = bsum[gc];
        const int pc = ((gc & 255) << 2) | (gc >> 8);   // gate-interleaved column
        #pragma unroll
        for (int i = 0; i < 4; ++i) {
            #pragma unroll
            for (int q = 0; q < 4; ++q) {
                const int gr = mt*128 + wm*64 + i*16 + kg*4 + q;
                xg[(size_t)gr*G4_ + pc] = (f16)(acc[i][j][q] + bs);
            }
        }
    }
}

// ---------------- recurrence: round-8 geometry, B-frags pinned to AGPRs ----------------
// A = h broadcast to all 16 rows (LDS addr depends only on lane>>4) -> D rows
// identical -> every lane holds p[G = nt*16 + (lane&15)] in acc reg 0.
// Wave wv covers gates q*256 + wv*32 + {0..31}: all 4 gate types of j-block ->
// c/h update fully in-lane (16-fold replicated; lanes<16 write h & pool).
__global__ __attribute__((amdgpu_flat_work_group_size(512, 512), amdgpu_waves_per_eu(2)))
void recur_k(const f16* __restrict__ xg,
             const uint4* __restrict__ wreg_g, const uint4* __restrict__ wlds_g,
             const unsigned* __restrict__ mb,
             float* __restrict__ pool)
{
    extern __shared__ char smem[];
    const int tid = threadIdx.x, b = blockIdx.x;
    const int wv = tid >> 6, lane = tid & 63;
    const int li = lane & 15, lq16 = (lane >> 4) * 16;
    const int j0 = wv*32 + li, j1 = j0 + 16;

    // register-resident B fragments — ALL pinned to AGPRs (MFMA-native operands)
    f16x8 wb[45];
    #pragma unroll
    for (int f = 0; f < 45; ++f)
        wb[f] = *(const f16x8*)(wreg_g + (size_t)f*512 + tid);
    #pragma unroll
    for (int f = 0; f < 45; ++f) asm volatile("" : "+a"(wb[f]));
    // LDS-resident B fragments
    {
        uint4* wl = (uint4*)smem;
        #pragma unroll
        for (int s = 0; s < 19; ++s)
            wl[(wv*19 + s)*64 + lane] = wlds_g[(wv*19 + s)*64 + lane];
    }
    if (tid < 256) ((unsigned*)(smem + HB_OFF))[tid] = 0u;   // zero both h buffers

    const char* xgrow = (const char*)xg + (size_t)b * T_ * 2048;
    const char* wbase = smem + wv*19*1024;
    float c0 = 0.f, c1 = 0.f, pooled0 = 0.f, pooled1 = 0.f;
    const f32x4 zero4 = {0.f, 0.f, 0.f, 0.f};
    unsigned mw = 0;
    __syncthreads();

    for (int t = 0; t < T_; ++t) {
        const char* hb = smem + HB_OFF + (t & 1)*512;
        uint2 xv0 = *(const uint2*)(xgrow + (size_t)t*2048 + j0*8);
        uint2 xv1 = *(const uint2*)(xgrow + (size_t)t*2048 + j1*8);
        if ((t & 31) == 0) mw = mb[b*64 + (t >> 5)];

        // batch-issue all 8 A-fragment reads (independent addresses)
        f16x8 a[8];
        #pragma unroll
        for (int kt = 0; kt < 8; ++kt)
            a[kt] = *(const f16x8*)(hb + kt*64 + lq16);

        f32x4 acc[8];
        // kt 0: fresh accumulators via zero-C MFMA
        #pragma unroll
        for (int qc = 0; qc < 8; ++qc)
            acc[qc] = __builtin_amdgcn_mfma_f32_16x16x32_f16(a[0], wb[qc], zero4, 0, 0, 0);
        // kt 1..4: register B
        #pragma unroll
        for (int kt = 1; kt < 5; ++kt)
            #pragma unroll
            for (int qc = 0; qc < 8; ++qc)
                acc[qc] = __builtin_amdgcn_mfma_f32_16x16x32_f16(a[kt], wb[kt*8 + qc], acc[qc], 0, 0, 0);
        // kt 5: 5 register + 3 LDS frags
        #pragma unroll
        for (int qc = 0; qc < 5; ++qc)
            acc[qc] = __builtin_amdgcn_mfma_f32_16x16x32_f16(a[5], wb[40 + qc], acc[qc], 0, 0, 0);
        #pragma unroll
        for (int s = 0; s < 3; ++s) {
            f16x8 wl = *(const f16x8*)(wbase + s*1024 + lane*16);
            acc[5 + s] = __builtin_amdgcn_mfma_f32_16x16x32_f16(a[5], wl, acc[5 + s], 0, 0, 0);
        }
        // kt 6: LDS frags s=3..10
        #pragma unroll
        for (int qc = 0; qc < 8; ++qc) {
            f16x8 wl = *(const f16x8*)(wbase + (3 + qc)*1024 + lane*16);
            acc[qc] = __builtin_amdgcn_mfma_f32_16x16x32_f16(a[6], wl, acc[qc], 0, 0, 0);
        }
        // kt 7: LDS frags s=11..18
        #pragma unroll
        for (int qc = 0; qc < 8; ++qc) {
            f16x8 wl = *(const f16x8*)(wbase + (11 + qc)*1024 + lane*16);
            acc[qc] = __builtin_amdgcn_mfma_f32_16x16x32_f16(a[7], wl, acc[qc], 0, 0, 0);
        }

        // gate tail, fully in-lane (acc[q*2+c][0] = p for gate q of j_c)
        const f16x2 xa0 = __builtin_bit_cast(f16x2, xv0.x);
        const f16x2 xb0 = __builtin_bit_cast(f16x2, xv0.y);
        const f16x2 xa1 = __builtin_bit_cast(f16x2, xv1.x);
        const f16x2 xb1 = __builtin_bit_cast(f16x2, xv1.y);
        const float gi0 = sigm (acc[0][0] + (float)xa0.x);
        const float gf0 = sigm (acc[2][0] + (float)xa0.y);
        const float gg0 = tanhr(acc[4][0] + (float)xb0.x);
        const float go0 = sigm (acc[6][0] + (float)xb0.y);
        const float gi1 = sigm (acc[1][0] + (float)xa1.x);
        const float gf1 = sigm (acc[3][0] + (float)xa1.y);
        const float gg1 = tanhr(acc[5][0] + (float)xb1.x);
        const float go1 = sigm (acc[7][0] + (float)xb1.y);
        c0 = gf0*c0 + gi0*gg0;
        c1 = gf1*c1 + gi1*gg1;
        const float h0 = go0 * tanhr(c0);
        const float h1 = go1 * tanhr(c1);
        const float madd = ((mw >> (t & 31)) & 1) ? 1.f : 0.f;
        pooled0 += madd * h0;
        pooled1 += madd * h1;
        char* hn = smem + HB_OFF + ((t + 1) & 1)*512;
        if (lane < 16) {
            *(f16*)(hn + j0*2) = (f16)h0;
            *(f16*)(hn + j1*2) = (f16)h1;
        }
        __syncthreads();
    }
    if (lane < 16) {
        pool[b*H_ + j0] = pooled0;
        pool[b*H_ + j1] = pooled1;
    }
}

// ---------------- head: len scan + pooled mean -> relu(lin1) -> lin2 ----------------
__global__ __launch_bounds__(256) void head_k(
    const int* __restrict__ x,
    const float* __restrict__ pool,
    const float* __restrict__ w1, const float* __restrict__ b1,
    const float* __restrict__ w2, const float* __restrict__ b2,
    float* __restrict__ out)
{
    __shared__ float pl[256];
    __shared__ float l1[512];
    __shared__ int wcnt[4];
    const int b = blockIdx.x, tid = threadIdx.x;
    const int is64 = detect64(x);
    const int* xrow = x + (((size_t)b * T_) << is64);
    int cnt = 0;
    for (int k = tid; k < T_; k += 256) cnt += (xrow[(size_t)k << is64] != 0);
    #pragma unroll
    for (int s = 32; s > 0; s >>= 1) cnt += __shfl_xor(cnt, s);
    if ((tid & 63) == 0) wcnt[tid >> 6] = cnt;
    __syncthreads();
    const float inv = 1.f / (float)(wcnt[0] + wcnt[1] + wcnt[2] + wcnt[3]);
    pl[tid] = pool[b*256 + tid] * inv;
    __syncthreads();
    for (int o = tid; o < 512; o += 256) {
        const float4* wrow = (const float4*)(w1 + (size_t)o*256);
        float s = b1[o];
        #pragma unroll 8
        for (int k = 0; k < 64; ++k) {
            float4 wv = wrow[k];
            s += pl[k*4+0]*wv.x + pl[k*4+1]*wv.y + pl[k*4+2]*wv.z + pl[k*4+3]*wv.w;
        }
        l1[o] = fmaxf(s, 0.f);
    }
    __syncthreads();
    if (tid < 20) {
        const float4* wrow = (const float4*)(w2 + (size_t)tid*512);
        float s = b2[tid];
        #pragma unroll 8
        for (int k = 0; k < 128; ++k) {
            float4 wv = wrow[k];
            s += l1[k*4+0]*wv.x + l1[k*4+1]*wv.y + l1[k*4+2]*wv.z + l1[k*4+3]*wv.w;
        }
        out[b*20 + tid] = s;
    }
}

extern "C" void kernel_launch(void* const* d_in, const int* in_sizes, int n_in,
                              void* d_out, int out_size, void* d_ws, size_t ws_size,
                              hipStream_t stream) {
    (void)in_sizes; (void)n_in; (void)out_size; (void)ws_size;
    const int*   x    = (const int*)d_in[0];
    const float* emb  = (const float*)d_in[1];
    const float* w_ih = (const float*)d_in[2];
    const float* w_hh = (const float*)d_in[3];
    const float* b_ih = (const float*)d_in[4];
    const float* b_hh = (const float*)d_in[5];
    const float* w1   = (const float*)d_in[6];
    const float* b1   = (const float*)d_in[7];
    const float* w2   = (const float*)d_in[8];
    const float* b2   = (const float*)d_in[9];
    float* out = (float*)d_out;
    char* ws = (char*)d_ws;

    f16*      xg    = (f16*)(ws + WS_XG);
    f16*      wih16 = (f16*)(ws + WS_WIH);
    uint4*    wreg  = (uint4*)(ws + WS_WREG);
    uint4*    wlds  = (uint4*)(ws + WS_WLDS);
    unsigned* mb    = (unsigned*)(ws + WS_MB);
    float*    bsum  = (float*)(ws + WS_BSUM);
    float*    pool  = (float*)(ws + WS_POOL);

    hipLaunchKernelGGL(prep_k, dim3(512), dim3(256), 0, stream,
                       x, w_ih, w_hh, b_ih, b_hh, wih16, wreg, wlds, mb, bsum);
    hipLaunchKernelGGL(gemm_xg_k, dim3(4096), dim3(256), 0, stream,
                       x, emb, wih16, bsum, xg);
    hipLaunchKernelGGL(recur_k, dim3(32), dim3(512), LDS_BYTES, stream,
                       xg, wreg, wlds, mb, pool);
    hipLaunchKernelGGL(head_k, dim3(32), dim3(256), 0, stream,
                       x, pool, w1, b1, w2, b2, out);
}